// Round 10
// baseline (272.113 us; speedup 1.0000x reference)
//
#include <hip/hip_runtime.h>
#include <hip/hip_bf16.h>

typedef __bf16 bf16x8 __attribute__((ext_vector_type(8)));
typedef float f32x4 __attribute__((ext_vector_type(4)));

#define EPSBN 1e-3f

constexpr int NPIX = 4096;   // H*W
constexpr int D2 = 256;      // C/2

#define RAW_BARRIER() do { \
  asm volatile("s_waitcnt lgkmcnt(0)" ::: "memory"); \
  __builtin_amdgcn_s_barrier(); \
  asm volatile("" ::: "memory"); \
} while (0)

// ---------- fused prep: cvt + WfghT + bias384 + WcatT(+wow dot) + biasF ----------
// Block ranges (all independent; no intra-kernel ordering assumed):
//   [0,768)        WfghT
//   [768,770)      bias384
//   [770,8962)     x -> xb (bf16)
//   [8962,9474)    WcatT k<256  (wow dot inline)
//   [9474,10498)   WcatT k>=256
//   [10498,10500)  biasF
__global__ __launch_bounds__(256) void kp_prep(const float* __restrict__ x,
                                               const float* __restrict__ wf,
                                               const float* __restrict__ wg,
                                               const float* __restrict__ wh,
                                               const float* __restrict__ bf_,
                                               const float* __restrict__ bg_,
                                               const float* __restrict__ bh_,
                                               const float* __restrict__ wo,
                                               const float* __restrict__ bo,
                                               const float* __restrict__ gamma,
                                               const float* __restrict__ wc,
                                               const float* __restrict__ bc,
                                               const float* __restrict__ bns,
                                               const float* __restrict__ bnb,
                                               const float* __restrict__ bnm,
                                               const float* __restrict__ bnv,
                                               __bf16* __restrict__ xb,
                                               __bf16* __restrict__ WfghT,
                                               float* __restrict__ bias384,
                                               __bf16* __restrict__ WcatT,
                                               float* __restrict__ biasF) {
  const int bid = blockIdx.x, tid = threadIdx.x;
  if (bid < 768) {                      // WfghT[c][k], 384x512
    int idx = bid * 256 + tid;
    int c = idx >> 9, k = idx & 511;
    float v = (c < 64) ? wf[k * 64 + c] : (c < 128) ? wg[k * 64 + (c - 64)] : wh[k * 256 + (c - 128)];
    WfghT[idx] = (__bf16)v;
  } else if (bid < 770) {               // bias384
    int c = (bid - 768) * 256 + tid;
    if (c < 384) bias384[c] = (c < 64) ? bf_[c] : (c < 128) ? bg_[c - 64] : bh_[c - 128];
  } else if (bid < 8962) {              // x -> bf16 (float4 groups)
    int i = (bid - 770) * 256 + tid;    // < 2097152
    float4 v = reinterpret_cast<const float4*>(x)[i];
    union { __bf16 h[4]; uint2 u; } o;
    o.h[0] = (__bf16)v.x; o.h[1] = (__bf16)v.y; o.h[2] = (__bf16)v.z; o.h[3] = (__bf16)v.w;
    reinterpret_cast<uint2*>(xb)[i] = o.u;
  } else if (bid < 9474) {              // WcatT[c][d], d<256: gamma * (wo@wc)[d][c] * s[c]
    int idx = (bid - 8962) * 256 + tid; // d*512+c mapping (wo row broadcast, wc coalesced)
    int d = idx >> 9, c = idx & 511;
    float a0 = 0.f, a1 = 0.f, a2 = 0.f, a3 = 0.f;
    for (int j = 0; j < 512; j += 4) {
      float4 w4 = *reinterpret_cast<const float4*>(wo + d * 512 + j);
      a0 += w4.x * wc[(size_t)j * 512 + c];
      a1 += w4.y * wc[(size_t)(j + 1) * 512 + c];
      a2 += w4.z * wc[(size_t)(j + 2) * 512 + c];
      a3 += w4.w * wc[(size_t)(j + 3) * 512 + c];
    }
    float s = bns[c] * rsqrtf(bnv[c] + EPSBN);
    WcatT[(size_t)c * 768 + d] = (__bf16)(gamma[0] * ((a0 + a1) + (a2 + a3)) * s);
  } else if (bid < 10498) {             // WcatT[c][256+kk] = (wc_top+wc_bot)[kk][c]*s[c]
    int idx = (bid - 9474) * 256 + tid; // c*512+kk mapping (write coalesced)
    int c = idx >> 9, kk = idx & 511;
    float s = bns[c] * rsqrtf(bnv[c] + EPSBN);
    float v = (wc[(size_t)kk * 512 + c] + wc[(size_t)(512 + kk) * 512 + c]) * s;
    WcatT[(size_t)c * 768 + 256 + kk] = (__bf16)v;
  } else {                              // biasF
    int c = (bid - 10498) * 256 + tid;  // < 512
    float s = bns[c] * rsqrtf(bnv[c] + EPSBN);
    float a0 = 0.f, a1 = 0.f, a2 = 0.f, a3 = 0.f;
    for (int j = 0; j < 512; j += 4) {
      a0 += bo[j] * wc[(size_t)j * 512 + c];
      a1 += bo[j + 1] * wc[(size_t)(j + 1) * 512 + c];
      a2 += bo[j + 2] * wc[(size_t)(j + 2) * 512 + c];
      a3 += bo[j + 3] * wc[(size_t)(j + 3) * 512 + c];
    }
    float pre = bc[c] + gamma[0] * ((a0 + a1) + (a2 + a3));
    biasF[c] = (pre - bnm[c]) * s + bnb[c];
  }
}

// ---------- MFMA GEMM, BN=128: C[M][NC] = A[M][KT] @ WT^T + bias ----------
// 256 thr = 4 waves in 2x2; per-wave 64m x 64n (acc 4x4).
// MODE 0: n0==0 -> fg [M][128] bf16; n0>=128 -> hvT [B][256][4096] via LDS transpose
// MODE 1: float out [M][NC], relu
template <int KT, int NC, int MODE>
__global__ __launch_bounds__(256) void k_gemm(const __bf16* __restrict__ A1, int k1, int lda1,
                                              const __bf16* __restrict__ A2, int lda2,
                                              const __bf16* __restrict__ WT,
                                              const float* __restrict__ bias,
                                              void* __restrict__ out1,
                                              void* __restrict__ out2) {
  __shared__ __bf16 SH[256][72];        // rows [0,128)=A-tile, [128,256)=B-tile
  const int m0 = blockIdx.x * 128, n0 = blockIdx.y * 128;
  const int tid = threadIdx.x, lane = tid & 63, w = tid >> 6;
  const int wr = w >> 1, wcl = w & 1;
  const int l15 = lane & 15, l4 = lane >> 4;
  f32x4 acc[4][4] = {};
  for (int ks = 0; ks < KT; ks += 64) {
    const __bf16* Asrc; int lda, kb;
    if (ks < k1) { Asrc = A1; lda = lda1; kb = ks; }
    else         { Asrc = A2; lda = lda2; kb = ks - k1; }
#pragma unroll
    for (int it = 0; it < 4; ++it) {
      int idx = it * 256 + tid, r = idx >> 3, ch = idx & 7;
      *(bf16x8*)(&SH[r][ch * 8]) = *(const bf16x8*)(Asrc + (size_t)(m0 + r) * lda + kb + ch * 8);
    }
#pragma unroll
    for (int it = 0; it < 4; ++it) {
      int idx = it * 256 + tid, r = idx >> 3, ch = idx & 7;
      *(bf16x8*)(&SH[128 + r][ch * 8]) = *(const bf16x8*)(WT + (size_t)(n0 + r) * KT + ks + ch * 8);
    }
    __syncthreads();
#pragma unroll
    for (int kk = 0; kk < 2; ++kk) {
      int krd = kk * 32 + l4 * 8;
      bf16x8 av[4], bv[4];
#pragma unroll
      for (int mi = 0; mi < 4; ++mi) av[mi] = *(const bf16x8*)(&SH[wr * 64 + mi * 16 + l15][krd]);
#pragma unroll
      for (int ni = 0; ni < 4; ++ni) bv[ni] = *(const bf16x8*)(&SH[128 + wcl * 64 + ni * 16 + l15][krd]);
#pragma unroll
      for (int mi = 0; mi < 4; ++mi)
#pragma unroll
        for (int ni = 0; ni < 4; ++ni)
          acc[mi][ni] = __builtin_amdgcn_mfma_f32_16x16x32_bf16(av[mi], bv[ni], acc[mi][ni], 0, 0, 0);
    }
    __syncthreads();
  }
  if (MODE == 1) {
    float* out = (float*)out1;
#pragma unroll
    for (int mi = 0; mi < 4; ++mi)
#pragma unroll
      for (int ni = 0; ni < 4; ++ni) {
        int col = n0 + wcl * 64 + ni * 16 + l15;
        float bcol = bias[col];
        int row0 = m0 + wr * 64 + mi * 16 + l4 * 4;
#pragma unroll
        for (int r = 0; r < 4; ++r)
          out[(size_t)(row0 + r) * NC + col] = fmaxf(acc[mi][ni][r] + bcol, 0.f);
      }
  } else if (n0 == 0) {
    // fg path (all 128 cols)
    __bf16* fg = (__bf16*)out1;
#pragma unroll
    for (int mi = 0; mi < 4; ++mi)
#pragma unroll
      for (int ni = 0; ni < 4; ++ni) {
        int col = wcl * 64 + ni * 16 + l15;
        float bcol = bias[col];
        int row0 = m0 + wr * 64 + mi * 16 + l4 * 4;
#pragma unroll
        for (int r = 0; r < 4; ++r)
          fg[(size_t)(row0 + r) * 128 + col] = (__bf16)(acc[mi][ni][r] + bcol);
      }
  } else {
    // hvT path: transpose 128n x 128d through LDS (re-uses SH: 128x136 = 34.8KB <= 36.9KB)
    __syncthreads();
    __bf16 (*Tt)[136] = (__bf16(*)[136])(&SH[0][0]);
#pragma unroll
    for (int mi = 0; mi < 4; ++mi)
#pragma unroll
      for (int ni = 0; ni < 4; ++ni) {
        int dloc = wcl * 64 + ni * 16 + l15;
        float bcol = bias[n0 + dloc];
        int nloc = wr * 64 + mi * 16 + l4 * 4;
#pragma unroll
        for (int r = 0; r < 4; ++r)
          Tt[dloc][nloc + r] = (__bf16)(acc[mi][ni][r] + bcol);
      }
    __syncthreads();
    const int bb = m0 >> 12, n = m0 & 4095, d0 = n0 - 128;
    __bf16* hvT = (__bf16*)out2;
    const int rrow = tid >> 1, c8 = tid & 1;  // 128 rows x 2 chunk-threads
    __bf16* dst = hvT + ((size_t)(bb * 256 + d0 + rrow)) * 4096 + n;
#pragma unroll
    for (int j = 0; j < 8; ++j)
      *(bf16x8*)(dst + c8 * 64 + j * 8) = *(const bf16x8*)(&Tt[rrow][c8 * 64 + j * 8]);
  }
}

// ---------- attention (R8 proven: QBLK=64, grid 256, 2-deep V prefetch) ----------
__global__ __launch_bounds__(512, 2) void k_attn(const __bf16* __restrict__ fg,
                                                 const __bf16* __restrict__ hvT,
                                                 __bf16* __restrict__ obuf) {
  __shared__ __bf16 PsT[2][64][136];
  __shared__ float Lp[8][64];
  const int id = blockIdx.x;
  const int xcd = id & 7, i2 = id >> 3;
  const int b = xcd >> 1;
  const int q0 = (i2 * 2 + (xcd & 1)) * 64;
  const int tid = threadIdx.x, w = tid >> 6, lane = tid & 63;
  const int l15 = lane & 15, l4 = lane >> 4;
  const __bf16* fgb = fg + (size_t)b * NPIX * 128;
  const __bf16* vb = hvT + (size_t)b * D2 * NPIX;

  bf16x8 bG[4][2];
#pragma unroll
  for (int qt = 0; qt < 4; ++qt)
#pragma unroll
    for (int kk = 0; kk < 2; ++kk)
      bG[qt][kk] = *(const bf16x8*)(fgb + (size_t)(q0 + qt * 16 + l15) * 128 + 64 + kk * 32 + l4 * 8);

  bf16x8 aF[2], bVA[2][4], bVB[2][4];
#pragma unroll
  for (int kk = 0; kk < 2; ++kk)
    aF[kk] = *(const bf16x8*)(fgb + (size_t)(w * 16 + l15) * 128 + kk * 32 + l4 * 8);
#pragma unroll
  for (int dj = 0; dj < 2; ++dj)
#pragma unroll
    for (int k4 = 0; k4 < 4; ++k4) {
      bVA[dj][k4] = *(const bf16x8*)(vb + (size_t)(w * 32 + dj * 16 + l15) * NPIX + k4 * 32 + l4 * 8);
      bVB[dj][k4] = *(const bf16x8*)(vb + (size_t)(w * 32 + dj * 16 + l15) * NPIX + 128 + k4 * 32 + l4 * 8);
    }

  f32x4 accO[4][2] = {};
  float lsum[4] = {0.f, 0.f, 0.f, 0.f};

#define ABODY(T, BV) do {                                                               \
    const int mn1 = (((T) + 1) * 128) & (NPIX - 1);                                     \
    const int mn2 = (((T) + 2) * 128) & (NPIX - 1);                                     \
    const int bufi = (T) & 1;                                                           \
    f32x4 s[4];                                                                         \
    _Pragma("unroll")                                                                   \
    for (int qt = 0; qt < 4; ++qt) {                                                    \
      s[qt] = (f32x4){0.f, 0.f, 0.f, 0.f};                                              \
      _Pragma("unroll")                                                                 \
      for (int kk = 0; kk < 2; ++kk)                                                    \
        s[qt] = __builtin_amdgcn_mfma_f32_16x16x32_bf16(aF[kk], bG[qt][kk], s[qt], 0, 0, 0); \
    }                                                                                   \
    bf16x8 aFn[2];                                                                      \
    _Pragma("unroll")                                                                   \
    for (int kk = 0; kk < 2; ++kk)                                                      \
      aFn[kk] = *(const bf16x8*)(fgb + (size_t)(mn1 + w * 16 + l15) * 128 + kk * 32 + l4 * 8); \
    _Pragma("unroll")                                                                   \
    for (int qt = 0; qt < 4; ++qt) {                                                    \
      float p0 = __expf(s[qt][0]), p1 = __expf(s[qt][1]);                               \
      float p2 = __expf(s[qt][2]), p3 = __expf(s[qt][3]);                               \
      lsum[qt] += (p0 + p1) + (p2 + p3);                                                \
      union { __bf16 h[4]; uint2 u; } pk;                                               \
      pk.h[0] = (__bf16)p0; pk.h[1] = (__bf16)p1;                                       \
      pk.h[2] = (__bf16)p2; pk.h[3] = (__bf16)p3;                                       \
      *(uint2*)(&PsT[bufi][qt * 16 + l15][w * 16 + l4 * 4]) = pk.u;                     \
    }                                                                                   \
    RAW_BARRIER();                                                                      \
    _Pragma("unroll")                                                                   \
    for (int qt = 0; qt < 4; ++qt) {                                                    \
      bf16x8 aP[4];                                                                     \
      _Pragma("unroll")                                                                 \
      for (int k4 = 0; k4 < 4; ++k4)                                                    \
        aP[k4] = *(const bf16x8*)(&PsT[bufi][qt * 16 + l15][k4 * 32 + l4 * 8]);         \
      _Pragma("unroll")                                                                 \
      for (int dj = 0; dj < 2; ++dj)                                                    \
        _Pragma("unroll")                                                               \
        for (int k4 = 0; k4 < 4; ++k4)                                                  \
          accO[qt][dj] = __builtin_amdgcn_mfma_f32_16x16x32_bf16(aP[k4], BV[dj][k4], accO[qt][dj], 0, 0, 0); \
    }                                                                                   \
    _Pragma("unroll")                                                                   \
    for (int dj = 0; dj < 2; ++dj)                                                      \
      _Pragma("unroll")                                                                 \
      for (int k4 = 0; k4 < 4; ++k4)                                                    \
        BV[dj][k4] = *(const bf16x8*)(vb + (size_t)(w * 32 + dj * 16 + l15) * NPIX + mn2 + k4 * 32 + l4 * 8); \
    aF[0] = aFn[0]; aF[1] = aFn[1];                                                     \
  } while (0)

  for (int t = 0; t < 32; t += 2) {
    ABODY(t, bVA);
    ABODY(t + 1, bVB);
  }
#undef ABODY

#pragma unroll
  for (int qt = 0; qt < 4; ++qt) {
    float v = lsum[qt];
    v += __shfl_xor(v, 16); v += __shfl_xor(v, 32);
    lsum[qt] = v;
  }
  if (l4 == 0) {
#pragma unroll
    for (int qt = 0; qt < 4; ++qt) Lp[w][qt * 16 + l15] = lsum[qt];
  }
  __syncthreads();
  float inv[4][4];
#pragma unroll
  for (int qt = 0; qt < 4; ++qt)
#pragma unroll
    for (int r = 0; r < 4; ++r) {
      int q = qt * 16 + l4 * 4 + r;
      float lt = 0.f;
#pragma unroll
      for (int ww = 0; ww < 8; ++ww) lt += Lp[ww][q];
      inv[qt][r] = 1.0f / lt;
    }
  __bf16* ob = obuf + ((size_t)b * NPIX + q0) * D2;
#pragma unroll
  for (int qt = 0; qt < 4; ++qt)
#pragma unroll
    for (int dj = 0; dj < 2; ++dj)
#pragma unroll
      for (int r = 0; r < 4; ++r)
        ob[(size_t)(qt * 16 + l4 * 4 + r) * D2 + w * 32 + dj * 16 + l15] =
            (__bf16)(accO[qt][dj][r] * inv[qt][r]);
}

// ---------- launch ----------
extern "C" void kernel_launch(void* const* d_in, const int* in_sizes, int n_in,
                              void* d_out, int out_size, void* d_ws, size_t ws_size,
                              hipStream_t stream) {
  const float* x = (const float*)d_in[0];
  const float* wf = (const float*)d_in[1];
  const float* bf_ = (const float*)d_in[2];
  const float* wg = (const float*)d_in[3];
  const float* bg_ = (const float*)d_in[4];
  const float* wh = (const float*)d_in[5];
  const float* bh_ = (const float*)d_in[6];
  const float* wo = (const float*)d_in[7];
  const float* bo = (const float*)d_in[8];
  const float* gamma = (const float*)d_in[9];
  const float* wc = (const float*)d_in[10];
  const float* bc = (const float*)d_in[11];
  const float* bns = (const float*)d_in[12];
  const float* bnb = (const float*)d_in[13];
  const float* bnm = (const float*)d_in[14];
  const float* bnv = (const float*)d_in[15];
  (void)in_sizes; (void)n_in; (void)out_size; (void)ws_size;

  char* ws = (char*)d_ws;
  __bf16* xb     = (__bf16*)(ws + 0);          // 16384*512*2  = 16,777,216
  __bf16* fg     = (__bf16*)(ws + 16777216);   // 16384*128*2  =  4,194,304
  __bf16* hvT    = (__bf16*)(ws + 20971520);   // 4*256*4096*2 =  8,388,608
  __bf16* obuf   = (__bf16*)(ws + 29360128);   // 16384*256*2  =  8,388,608
  __bf16* WfghT  = (__bf16*)(ws + 37748736);   // 384*512*2    =    393,216
  float*  bias384= (float*) (ws + 38141952);   // 384*4
  __bf16* WcatT  = (__bf16*)(ws + 38143488);   // 512*768*2    =    786,432
  float*  biasF  = (float*) (ws + 38929920);   // 512*4  -> total ~38.9 MB
  float* out = (float*)d_out;

  hipLaunchKernelGGL(kp_prep, dim3(10500), dim3(256), 0, stream,
                     x, wf, wg, wh, bf_, bg_, bh_, wo, bo, gamma, wc, bc,
                     bns, bnb, bnm, bnv, xb, WfghT, bias384, WcatT, biasF);
  hipLaunchKernelGGL((k_gemm<512, 384, 0>), dim3(128, 3), dim3(256), 0, stream,
                     xb, 512, 512, xb, 512, WfghT, bias384, (void*)fg, (void*)hvT);
  hipLaunchKernelGGL(k_attn, dim3(256), dim3(512), 0, stream, fg, hvT, obuf);
  hipLaunchKernelGGL((k_gemm<768, 512, 1>), dim3(128, 4), dim3(256), 0, stream,
                     obuf, 256, 256, xb, 512, WcatT, biasF, (void*)out, nullptr);
}